// Round 1
// baseline (988.468 us; speedup 1.0000x reference)
//
#include <hip/hip_runtime.h>
#include <math.h>

// VQ tokenizer fused forward, fp32 end-to-end (argmin exactness requires it).
// Shapes: x[131072,384] @ W1[384,256] -> LN -> GELU -> @ W2[256,128] -> LN -> z
//         dist to codebook[256,128], argmin, gather, losses, straight-through.
//
// ws layout (floats): [0,32768) cbT[128][256] ; [32768,33024) se[256] ;
//                     [33024,37120) per-block loss partials[4096]
// d_out layout (floats): [0,16777216) z_q_st ; [16777216] loss ; [16777217,+131072) indices (as float)

#define BR 32
#define XS 388   // x tile LDS stride  (384+4: b128-aligned, conflict-free row reads)
#define HS 260   // h tile LDS stride  (256+4)
#define ZS 132   // z tile LDS stride  (128+4)

__device__ __forceinline__ float gelu_exact(float v) {
    return 0.5f * v * (1.0f + erff(v * 0.70710678118654752440f));
}

// Transpose codebook to k-major + compute per-code squared norms.
__global__ __launch_bounds__(256) void k_prep(const float* __restrict__ cb,
                                              float* __restrict__ cbT,
                                              float* __restrict__ se) {
    int g = blockIdx.x * 256 + threadIdx.x;      // 8192 threads: 256 codes x 32 float4
    int code = g >> 5, q = g & 31;
    float4 v = reinterpret_cast<const float4*>(cb)[code * 32 + q];
    float s = v.x * v.x + v.y * v.y + v.z * v.z + v.w * v.w;
    #pragma unroll
    for (int off = 16; off; off >>= 1) s += __shfl_xor(s, off, 32);
    if (q == 0) se[code] = s;
    int k0 = q * 4;
    cbT[(k0 + 0) * 256 + code] = v.x;
    cbT[(k0 + 1) * 256 + code] = v.y;
    cbT[(k0 + 2) * 256 + code] = v.z;
    cbT[(k0 + 3) * 256 + code] = v.w;
}

__global__ __launch_bounds__(256) void k_main(
    const float* __restrict__ x,
    const float* __restrict__ W1, const float* __restrict__ b1,
    const float* __restrict__ g1, const float* __restrict__ be1,
    const float* __restrict__ W2, const float* __restrict__ b2,
    const float* __restrict__ g2, const float* __restrict__ be2,
    const float* __restrict__ cb, const float* __restrict__ cbT,
    const float* __restrict__ se,
    float* __restrict__ out_z, float* __restrict__ out_idx,
    float* __restrict__ partials)
{
    // union buffer: xs [0,12416) ; hs [0,8320) ; zs [8320,12544)  (temporally disjoint)
    __shared__ float smem[12544];
    __shared__ float szs[BR];
    __shared__ int   idxs[BR];
    __shared__ float wsum[4];
    float* xs = smem;
    float* hs = smem;
    float* zs = smem + 8320;

    const int tid = threadIdx.x;
    const long row0 = (long)blockIdx.x * BR;

    // ---- phase 0: stage x tile [32][384] (global contiguous -> padded LDS) ----
    {
        const float4* xg = reinterpret_cast<const float4*>(x + row0 * 384);
        #pragma unroll
        for (int u = 0; u < 12; ++u) {
            int f = tid + 256 * u;               // 0..3071 float4s, contiguous in global
            int r = f / 96, c4 = f - r * 96;
            float4 v = xg[f];
            *reinterpret_cast<float4*>(&xs[r * XS + c4 * 4]) = v;
        }
    }
    __syncthreads();

    // ---- phase 1: GEMM1  h[32,256] = x @ W1 ;  thread tile 4 rows x 8 cols ----
    const int cg = tid & 31, rg = tid >> 5;      // cg: col group (8 cols), rg: row base
    const int c0 = cg * 8;
    float acc[4][8];
    #pragma unroll
    for (int i = 0; i < 4; ++i)
        #pragma unroll
        for (int j = 0; j < 8; ++j) acc[i][j] = 0.f;
    {
        const float4* w1p = reinterpret_cast<const float4*>(W1) + (c0 >> 2);
        for (int k = 0; k < 384; k += 4) {
            float4 xv[4];
            #pragma unroll
            for (int i = 0; i < 4; ++i)
                xv[i] = *reinterpret_cast<const float4*>(&xs[(rg + 8 * i) * XS + k]);
            #pragma unroll
            for (int dk = 0; dk < 4; ++dk) {
                float4 wa = w1p[(k + dk) * 64];
                float4 wb = w1p[(k + dk) * 64 + 1];
                #pragma unroll
                for (int i = 0; i < 4; ++i) {
                    float xx = reinterpret_cast<const float*>(&xv[i])[dk];
                    acc[i][0] = fmaf(xx, wa.x, acc[i][0]);
                    acc[i][1] = fmaf(xx, wa.y, acc[i][1]);
                    acc[i][2] = fmaf(xx, wa.z, acc[i][2]);
                    acc[i][3] = fmaf(xx, wa.w, acc[i][3]);
                    acc[i][4] = fmaf(xx, wb.x, acc[i][4]);
                    acc[i][5] = fmaf(xx, wb.y, acc[i][5]);
                    acc[i][6] = fmaf(xx, wb.z, acc[i][6]);
                    acc[i][7] = fmaf(xx, wb.w, acc[i][7]);
                }
            }
        }
    }
    // bias + LayerNorm(256) + GELU, in registers; row = half-wave (32 lanes share a row set)
    {
        float4 ba = reinterpret_cast<const float4*>(b1 + c0)[0];
        float4 bb = reinterpret_cast<const float4*>(b1 + c0)[1];
        float4 ga = reinterpret_cast<const float4*>(g1 + c0)[0];
        float4 gb = reinterpret_cast<const float4*>(g1 + c0)[1];
        float4 ea = reinterpret_cast<const float4*>(be1 + c0)[0];
        float4 eb = reinterpret_cast<const float4*>(be1 + c0)[1];
        float bv[8] = {ba.x, ba.y, ba.z, ba.w, bb.x, bb.y, bb.z, bb.w};
        float gv[8] = {ga.x, ga.y, ga.z, ga.w, gb.x, gb.y, gb.z, gb.w};
        float ev[8] = {ea.x, ea.y, ea.z, ea.w, eb.x, eb.y, eb.z, eb.w};
        #pragma unroll
        for (int i = 0; i < 4; ++i) {
            #pragma unroll
            for (int j = 0; j < 8; ++j) acc[i][j] += bv[j];
            float s = 0.f;
            #pragma unroll
            for (int j = 0; j < 8; ++j) s += acc[i][j];
            #pragma unroll
            for (int off = 16; off; off >>= 1) s += __shfl_xor(s, off, 32);
            float m = s * (1.0f / 256.0f);
            float t = 0.f;
            #pragma unroll
            for (int j = 0; j < 8; ++j) { float d = acc[i][j] - m; t += d * d; }
            #pragma unroll
            for (int off = 16; off; off >>= 1) t += __shfl_xor(t, off, 32);
            float inv = 1.0f / sqrtf(t * (1.0f / 256.0f) + 1e-5f);
            #pragma unroll
            for (int j = 0; j < 8; ++j) {
                float ln = (acc[i][j] - m) * inv * gv[j] + ev[j];
                acc[i][j] = gelu_exact(ln);
            }
        }
    }
    __syncthreads();   // all xs reads done before hs overwrites the union buffer
    #pragma unroll
    for (int i = 0; i < 4; ++i) {
        float4 p0 = make_float4(acc[i][0], acc[i][1], acc[i][2], acc[i][3]);
        float4 p1 = make_float4(acc[i][4], acc[i][5], acc[i][6], acc[i][7]);
        *reinterpret_cast<float4*>(&hs[(rg + 8 * i) * HS + c0]) = p0;
        *reinterpret_cast<float4*>(&hs[(rg + 8 * i) * HS + c0 + 4]) = p1;
    }
    __syncthreads();

    // ---- phase 2: GEMM2  z[32,128] = h @ W2 ; thread tile 2 rows x 8 cols ----
    const int cg2 = tid & 15, rg2 = tid >> 4;
    const int d0 = cg2 * 8;
    float a2[2][8];
    #pragma unroll
    for (int i = 0; i < 2; ++i)
        #pragma unroll
        for (int j = 0; j < 8; ++j) a2[i][j] = 0.f;
    {
        const float4* w2p = reinterpret_cast<const float4*>(W2) + (d0 >> 2);
        for (int k = 0; k < 256; k += 4) {
            float4 hv[2];
            hv[0] = *reinterpret_cast<const float4*>(&hs[rg2 * HS + k]);
            hv[1] = *reinterpret_cast<const float4*>(&hs[(rg2 + 16) * HS + k]);
            #pragma unroll
            for (int dk = 0; dk < 4; ++dk) {
                float4 wa = w2p[(k + dk) * 32];
                float4 wb = w2p[(k + dk) * 32 + 1];
                #pragma unroll
                for (int i = 0; i < 2; ++i) {
                    float xx = reinterpret_cast<const float*>(&hv[i])[dk];
                    a2[i][0] = fmaf(xx, wa.x, a2[i][0]);
                    a2[i][1] = fmaf(xx, wa.y, a2[i][1]);
                    a2[i][2] = fmaf(xx, wa.z, a2[i][2]);
                    a2[i][3] = fmaf(xx, wa.w, a2[i][3]);
                    a2[i][4] = fmaf(xx, wb.x, a2[i][4]);
                    a2[i][5] = fmaf(xx, wb.y, a2[i][5]);
                    a2[i][6] = fmaf(xx, wb.z, a2[i][6]);
                    a2[i][7] = fmaf(xx, wb.w, a2[i][7]);
                }
            }
        }
    }
    // bias + LayerNorm(128) + z->LDS + ||z||^2 ; row = 16-lane group
    {
        float4 ba = reinterpret_cast<const float4*>(b2 + d0)[0];
        float4 bb = reinterpret_cast<const float4*>(b2 + d0)[1];
        float4 ga = reinterpret_cast<const float4*>(g2 + d0)[0];
        float4 gb = reinterpret_cast<const float4*>(g2 + d0)[1];
        float4 ea = reinterpret_cast<const float4*>(be2 + d0)[0];
        float4 eb = reinterpret_cast<const float4*>(be2 + d0)[1];
        float bv[8] = {ba.x, ba.y, ba.z, ba.w, bb.x, bb.y, bb.z, bb.w};
        float gv[8] = {ga.x, ga.y, ga.z, ga.w, gb.x, gb.y, gb.z, gb.w};
        float ev[8] = {ea.x, ea.y, ea.z, ea.w, eb.x, eb.y, eb.z, eb.w};
        #pragma unroll
        for (int i = 0; i < 2; ++i) {
            int r = rg2 + 16 * i;
            #pragma unroll
            for (int j = 0; j < 8; ++j) a2[i][j] += bv[j];
            float s = 0.f;
            #pragma unroll
            for (int j = 0; j < 8; ++j) s += a2[i][j];
            #pragma unroll
            for (int off = 8; off; off >>= 1) s += __shfl_xor(s, off, 16);
            float m = s * (1.0f / 128.0f);
            float t = 0.f;
            #pragma unroll
            for (int j = 0; j < 8; ++j) { float d = a2[i][j] - m; t += d * d; }
            #pragma unroll
            for (int off = 8; off; off >>= 1) t += __shfl_xor(t, off, 16);
            float inv = 1.0f / sqrtf(t * (1.0f / 128.0f) + 1e-5f);
            float sz = 0.f;
            #pragma unroll
            for (int j = 0; j < 8; ++j) {
                float z = (a2[i][j] - m) * inv * gv[j] + ev[j];
                a2[i][j] = z;
                sz += z * z;
            }
            #pragma unroll
            for (int off = 8; off; off >>= 1) sz += __shfl_xor(sz, off, 16);
            if (cg2 == 0) szs[r] = sz;
            float4 p0 = make_float4(a2[i][0], a2[i][1], a2[i][2], a2[i][3]);
            float4 p1 = make_float4(a2[i][4], a2[i][5], a2[i][6], a2[i][7]);
            *reinterpret_cast<float4*>(&zs[r * ZS + d0]) = p0;
            *reinterpret_cast<float4*>(&zs[r * ZS + d0 + 4]) = p1;
        }
    }
    __syncthreads();

    // ---- phase 3: distances z @ cbT, argmin (ties -> lowest index) ----
    float ad[4][8];
    #pragma unroll
    for (int i = 0; i < 4; ++i)
        #pragma unroll
        for (int j = 0; j < 8; ++j) ad[i][j] = 0.f;
    {
        const float4* ctp = reinterpret_cast<const float4*>(cbT) + (c0 >> 2);
        for (int k = 0; k < 128; k += 4) {
            float4 zv[4];
            #pragma unroll
            for (int i = 0; i < 4; ++i)
                zv[i] = *reinterpret_cast<const float4*>(&zs[(rg + 8 * i) * ZS + k]);
            #pragma unroll
            for (int dk = 0; dk < 4; ++dk) {
                float4 wa = ctp[(k + dk) * 64];
                float4 wb = ctp[(k + dk) * 64 + 1];
                #pragma unroll
                for (int i = 0; i < 4; ++i) {
                    float xx = reinterpret_cast<const float*>(&zv[i])[dk];
                    ad[i][0] = fmaf(xx, wa.x, ad[i][0]);
                    ad[i][1] = fmaf(xx, wa.y, ad[i][1]);
                    ad[i][2] = fmaf(xx, wa.z, ad[i][2]);
                    ad[i][3] = fmaf(xx, wa.w, ad[i][3]);
                    ad[i][4] = fmaf(xx, wb.x, ad[i][4]);
                    ad[i][5] = fmaf(xx, wb.y, ad[i][5]);
                    ad[i][6] = fmaf(xx, wb.z, ad[i][6]);
                    ad[i][7] = fmaf(xx, wb.w, ad[i][7]);
                }
            }
        }
    }
    {
        float4 sa = reinterpret_cast<const float4*>(se + c0)[0];
        float4 sb = reinterpret_cast<const float4*>(se + c0)[1];
        float sev[8] = {sa.x, sa.y, sa.z, sa.w, sb.x, sb.y, sb.z, sb.w};
        #pragma unroll
        for (int i = 0; i < 4; ++i) {
            int r = rg + 8 * i;
            float szr = szs[r];
            float best = (szr + sev[0]) - 2.0f * ad[i][0];
            int bi = c0;
            #pragma unroll
            for (int j = 1; j < 8; ++j) {
                float d = (szr + sev[j]) - 2.0f * ad[i][j];
                if (d < best) { best = d; bi = c0 + j; }
            }
            #pragma unroll
            for (int off = 16; off; off >>= 1) {
                float od = __shfl_xor(best, off, 32);
                int   oi = __shfl_xor(bi,   off, 32);
                if (od < best || (od == best && oi < bi)) { best = od; bi = oi; }
            }
            if (cg == 0) idxs[r] = bi;
        }
    }
    __syncthreads();

    // ---- phase 4: gather z_q, straight-through output, loss partial ----
    float lsum = 0.f;
    {
        int orow = tid >> 3, part = tid & 7;
        long grow = row0 + orow;
        int bi = idxs[orow];
        const float4* cbr = reinterpret_cast<const float4*>(cb + bi * 128 + part * 16);
        float4* og = reinterpret_cast<float4*>(out_z + grow * 128 + part * 16);
        #pragma unroll
        for (int u = 0; u < 4; ++u) {
            float4 q = cbr[u];
            float4 zz = *reinterpret_cast<const float4*>(&zs[orow * ZS + part * 16 + u * 4]);
            float dx = q.x - zz.x, dy = q.y - zz.y, dz = q.z - zz.z, dw = q.w - zz.w;
            lsum += dx * dx + dy * dy + dz * dz + dw * dw;
            float4 o;  // replicate z + (z_q - z) rounding of the straight-through estimator
            o.x = zz.x + dx; o.y = zz.y + dy; o.z = zz.z + dz; o.w = zz.w + dw;
            og[u] = o;
        }
        if (part == 0) out_idx[grow] = (float)bi;
    }
    #pragma unroll
    for (int off = 32; off; off >>= 1) lsum += __shfl_xor(lsum, off, 64);
    if ((tid & 63) == 0) wsum[tid >> 6] = lsum;
    __syncthreads();
    if (tid == 0) partials[blockIdx.x] = (wsum[0] + wsum[1]) + (wsum[2] + wsum[3]);
}

__global__ __launch_bounds__(256) void k_loss(const float* __restrict__ partials,
                                              float* __restrict__ out_loss) {
    int tid = threadIdx.x;
    float s = 0.f;
    #pragma unroll
    for (int u = 0; u < 16; ++u) s += partials[tid + 256 * u];
    #pragma unroll
    for (int off = 32; off; off >>= 1) s += __shfl_xor(s, off, 64);
    __shared__ float ws2[4];
    if ((tid & 63) == 0) ws2[tid >> 6] = s;
    __syncthreads();
    if (tid == 0) {
        float tot = (ws2[0] + ws2[1]) + (ws2[2] + ws2[3]);
        float m = tot * (1.0f / 16777216.0f);
        out_loss[0] = m + 0.25f * m;   // codebook_loss + COMMIT * commitment_loss (equal values)
    }
}

extern "C" void kernel_launch(void* const* d_in, const int* in_sizes, int n_in,
                              void* d_out, int out_size, void* d_ws, size_t ws_size,
                              hipStream_t stream) {
    const float* emb = (const float*)d_in[0];
    const float* W1  = (const float*)d_in[1];
    const float* b1  = (const float*)d_in[2];
    const float* g1  = (const float*)d_in[3];
    const float* be1 = (const float*)d_in[4];
    const float* W2  = (const float*)d_in[5];
    const float* b2  = (const float*)d_in[6];
    const float* g2  = (const float*)d_in[7];
    const float* be2 = (const float*)d_in[8];
    const float* cb  = (const float*)d_in[9];

    float* out      = (float*)d_out;
    float* out_z    = out;                  // 131072*128 floats
    float* out_loss = out + 16777216;       // 1 float
    float* out_idx  = out + 16777217;       // 131072 floats (indices as float)

    float* cbT      = (float*)d_ws;         // needs ~148KB of ws
    float* se       = cbT + 32768;
    float* partials = se + 256;

    k_prep<<<32, 256, 0, stream>>>(cb, cbT, se);
    k_main<<<4096, 256, 0, stream>>>(emb, W1, b1, g1, be1, W2, b2, g2, be2,
                                     cb, cbT, se, out_z, out_idx, partials);
    k_loss<<<1, 256, 0, stream>>>(partials, out_loss);
}